// Round 6
// baseline (1239.015 us; speedup 1.0000x reference)
//
#include <hip/hip_runtime.h>
#include <hip/hip_bf16.h>

// Sinkhorn object matching, scaling-vector formulation, fp8 iteration,
// PERSISTENT kernel with PRODUCER/CONSUMER FLAG sync (no grid barrier,
// no atomics).
//   S = Q R^T (4096x4096, D=256), K0 = exp(S_aug/0.1), dustbin row/col = z
//   100x: u = 1/(K0 v); v = 1/(K0^T u);  K = diag(u) K0 diag(v); P interior.
// Block b (256 blocks, 1024 thr) holds rows [16b,16b+16) of A8=fp8(K0) AND of
// T8=fp8(K0^T) in LDS. 1 block/CU -> 256 blocks co-resident.
// Generation g=1..200 produces x_g (u for odd g, v for even) into ring slot
// xbuf[g&3]. Block b's wave 0 stores its 16 outputs (sc0sc1), waits vmcnt(0),
// then stores flags[b]=g (sc0sc1). Wave w of a consumer block polls the 16
// flags of the blocks that produce its x-strip [256w,256w+256). All cross-
// block data moves through sc0sc1 (device coherence point) -> no cache
// maintenance anywhere. Skew across blocks <=1 gen (per-block __syncthreads
// makes every block consume the full x vector) -> 4-slot ring is safe.

#define MROWS 4096
#define NCOLS 4096
#define DDIM 256
#define MP1 4097
#define INV_EPS 10.0f
#define NBLK 256
#define XSLOT 4104

typedef __attribute__((ext_vector_type(8))) short bf16x8;
typedef __attribute__((ext_vector_type(4))) float f32x4;
typedef __attribute__((ext_vector_type(2))) float f32x2;
typedef __attribute__((ext_vector_type(4))) unsigned short u16x4;

static __device__ __forceinline__ unsigned short f2bf(float f) {
  __hip_bfloat16 h = __float2bfloat16(f);
  union { __hip_bfloat16 h; unsigned short s; } c;
  c.h = h;
  return c.s;
}

// Coherent (L1/L2-bypassing) accessors. waitcnt lives inside the asm so the
// compiler cannot schedule uses between issue and completion (rule #18).
static __device__ __forceinline__ void ld2_coherent(const float* p0, const float* p1,
                                                    float4& a, float4& b) {
  asm volatile("global_load_dwordx4 %0, %2, off sc0 sc1\n\t"
               "global_load_dwordx4 %1, %3, off sc0 sc1\n\t"
               "s_waitcnt vmcnt(0)"
               : "=v"(a), "=v"(b)
               : "v"(p0), "v"(p1)
               : "memory");
}
static __device__ __forceinline__ void st_coherent(float* p, float x) {
  asm volatile("global_store_dword %0, %1, off sc0 sc1" :: "v"(p), "v"(x) : "memory");
}
static __device__ __forceinline__ unsigned ld_flagc(const unsigned* p) {
  unsigned r;
  asm volatile("global_load_dword %0, %1, off sc0 sc1\n\t"
               "s_waitcnt vmcnt(0)"
               : "=v"(r) : "v"(p) : "memory");
  return r;
}
static __device__ __forceinline__ void st_flag(unsigned* p, unsigned x) {
  asm volatile("global_store_dword %0, %1, off sc0 sc1" :: "v"(p), "v"(x) : "memory");
}

// ---------------------------------------------------------------------------
// MFMA bf16 GEMM: 128x128 tile, 4 waves (2x2), wave = 64x64 via 4x4 frags of
// 16x16x32. MODE 0: kv=exp(10S) -> fp8 A8[row][col], fp8 T8[col][row].
// MODE 1: val = u[row]*exp(10S)*v[col] -> fp32 K (stride MP1) and P.
// ---------------------------------------------------------------------------
template <int MODE>
__global__ __launch_bounds__(256) void mfma_gemm_kernel(
    const float* __restrict__ Q, const float* __restrict__ R,
    unsigned char* __restrict__ A8, unsigned char* __restrict__ T8,
    float* __restrict__ Kf, float* __restrict__ P,
    const float* __restrict__ u, const float* __restrict__ v)
{
  __shared__ unsigned short Qs[128][40];
  __shared__ unsigned short Rs[128][40];

  const int tid = threadIdx.x;
  const int lane = tid & 63;
  const int wid = tid >> 6;
  const int wy = wid >> 1;
  const int wx = wid & 1;
  const int rb = blockIdx.y * 128;
  const int cb = blockIdx.x * 128;
  const int lr = tid >> 3;
  const int lf = (tid & 7) * 4;

  f32x4 acc[4][4];
#pragma unroll
  for (int m = 0; m < 4; ++m)
#pragma unroll
    for (int n = 0; n < 4; ++n)
      acc[m][n] = (f32x4){0.f, 0.f, 0.f, 0.f};

  for (int k0 = 0; k0 < DDIM; k0 += 32) {
    float4 qv[4], rv[4];
#pragma unroll
    for (int i = 0; i < 4; ++i) {
      qv[i] = *reinterpret_cast<const float4*>(&Q[(size_t)(rb + lr + 32 * i) * DDIM + k0 + lf]);
      rv[i] = *reinterpret_cast<const float4*>(&R[(size_t)(cb + lr + 32 * i) * DDIM + k0 + lf]);
    }
    __syncthreads();
#pragma unroll
    for (int i = 0; i < 4; ++i) {
      u16x4 qs = {f2bf(qv[i].x), f2bf(qv[i].y), f2bf(qv[i].z), f2bf(qv[i].w)};
      u16x4 rs = {f2bf(rv[i].x), f2bf(rv[i].y), f2bf(rv[i].z), f2bf(rv[i].w)};
      *reinterpret_cast<u16x4*>(&Qs[lr + 32 * i][lf]) = qs;
      *reinterpret_cast<u16x4*>(&Rs[lr + 32 * i][lf]) = rs;
    }
    __syncthreads();

    const int ko = (lane >> 4) * 8;
    const int fr = lane & 15;
    bf16x8 af[4], bg[4];
#pragma unroll
    for (int m = 0; m < 4; ++m)
      af[m] = *reinterpret_cast<const bf16x8*>(&Qs[wy * 64 + m * 16 + fr][ko]);
#pragma unroll
    for (int n = 0; n < 4; ++n)
      bg[n] = *reinterpret_cast<const bf16x8*>(&Rs[wx * 64 + n * 16 + fr][ko]);
#pragma unroll
    for (int m = 0; m < 4; ++m)
#pragma unroll
      for (int n = 0; n < 4; ++n)
        acc[m][n] = __builtin_amdgcn_mfma_f32_16x16x32_bf16(af[m], bg[n], acc[m][n], 0, 0, 0);
  }

  // C/D layout (16x16x32): col = lane&15, row = (lane>>4)*4 + reg.
  const int r0 = (lane >> 4) * 4;
  const int fc = lane & 15;
#pragma unroll
  for (int m = 0; m < 4; ++m) {
    const int row0 = rb + wy * 64 + m * 16 + r0;
    float uu[4];
    if (MODE == 1) {
#pragma unroll
      for (int r = 0; r < 4; ++r) uu[r] = u[row0 + r];
    }
#pragma unroll
    for (int n = 0; n < 4; ++n) {
      const int col = cb + wx * 64 + n * 16 + fc;
      if (MODE == 0) {
        float kv[4];
#pragma unroll
        for (int r = 0; r < 4; ++r) kv[r] = __expf(acc[m][n][r] * INV_EPS);
        int packed = __builtin_amdgcn_cvt_pk_fp8_f32(kv[0], kv[1], 0, false);
        packed = __builtin_amdgcn_cvt_pk_fp8_f32(kv[2], kv[3], packed, true);
        *reinterpret_cast<unsigned int*>(&T8[(size_t)col * NCOLS + row0]) = (unsigned int)packed;
#pragma unroll
        for (int r = 0; r < 4; ++r)
          A8[(size_t)(row0 + r) * NCOLS + col] = (unsigned char)(((unsigned int)packed >> (8 * r)) & 0xffu);
      } else {
        const float vc = v[col];
#pragma unroll
        for (int r = 0; r < 4; ++r) {
          const float kv = __expf(acc[m][n][r] * INV_EPS);
          const float val = uu[r] * kv * vc;
          Kf[(size_t)(row0 + r) * MP1 + col] = val;
          P[(size_t)(row0 + r) * NCOLS + col] = val;
        }
      }
    }
  }
}

// ---------------------------------------------------------------------------
// xbuf slot 0 = ones (gen 0 = initial v); flags = 0 ("gen 0 done" for all).
// ---------------------------------------------------------------------------
__global__ void initv_kernel(float* __restrict__ xbuf, unsigned* __restrict__ flags)
{
  const int i = blockIdx.x * 1024 + threadIdx.x;
  if (i < MP1) xbuf[i] = 1.0f;
  if (i < NBLK) flags[i] = 0u;
}

// ---------------------------------------------------------------------------
// Final K dustbin row/col.
// ---------------------------------------------------------------------------
__global__ void edgeK_kernel(const float* __restrict__ zp, float* __restrict__ Kf,
                             const float* __restrict__ u, const float* __restrict__ v)
{
  const int i = blockIdx.x * 256 + threadIdx.x;
  if (i >= MP1) return;
  const float E = __expf(zp[0] * INV_EPS);
  Kf[(size_t)i * MP1 + NCOLS] = u[i] * E * v[NCOLS];
  Kf[(size_t)MROWS * MP1 + i] = u[MROWS] * E * v[i];
}

// ---------------------------------------------------------------------------
// Persistent Sinkhorn iteration kernel. 256 blocks x 1024 threads.
// Block b holds A8 rows [16b,16b+16) and T8 rows [16b,16b+16) in LDS.
// Gen g: out[16b+r] = 1/(sum_c lds[r][c]*x[c] + E*x[4096]); block 0 also
// out[4096] = 1/(E * sum_{j<=4096} x[j]).
// Wave w owns cols [256w,256w+256): polls flags[16w..16w+15] (the producers
// of that strip), loads its x strip, computes 16 partials, fold-butterfly
// reduce, scratch -> single __syncthreads -> wave 0 finale + flag publish.
// scratch/dscr double-buffered by g&1 so waves may run one gen ahead.
// ---------------------------------------------------------------------------
__global__ __launch_bounds__(1024) void sinkhorn_persist_kernel(
    const unsigned char* __restrict__ A8, const unsigned char* __restrict__ T8,
    float* __restrict__ xbuf, const float* __restrict__ zp,
    unsigned* __restrict__ flags)
{
  __shared__ unsigned char lA[16 * 4096];
  __shared__ unsigned char lT[16 * 4096];
  __shared__ float scratch[2][16][17];
  __shared__ float dscr[2][16];

  const int tid = threadIdx.x;
  const int b = blockIdx.x;
  const int lane = tid & 63;
  const int w = tid >> 6;
  const float E = __expf(zp[0] * INV_EPS);
  const int rev4 = ((lane & 1) << 3) | ((lane & 2) << 1) | ((lane & 4) >> 1) | ((lane & 8) >> 3);

  // one-time: stage this block's A and T row-slices into LDS (64KB each)
  {
    const uint4* gA = reinterpret_cast<const uint4*>(A8 + (size_t)b * 16 * 4096);
    const uint4* gT = reinterpret_cast<const uint4*>(T8 + (size_t)b * 16 * 4096);
    uint4* sA = reinterpret_cast<uint4*>(lA);
    uint4* sT = reinterpret_cast<uint4*>(lT);
#pragma unroll
    for (int i = 0; i < 4; ++i) {
      sA[tid + 1024 * i] = gA[tid + 1024 * i];
      sT[tid + 1024 * i] = gT[tid + 1024 * i];
    }
  }
  __syncthreads();

  const int c0 = (w << 8) + (lane << 2);              // lane's 4-col strip base
  const unsigned* fp = flags + ((w << 4) | (lane & 15));  // lane<16: producer flag

  for (int g = 1; g <= 200; ++g) {
    const unsigned char* Kl = (g & 1) ? lA : lT;      // odd g: u = f(v) uses A
    const float* xin = xbuf + (size_t)((g - 1) & 3) * XSLOT;
    float* xout = xbuf + (size_t)(g & 3) * XSLOT;
    const unsigned need = (unsigned)(g - 1);
    const int sb = g & 1;

    // wait for this wave's 16 producer blocks to publish gen g-1
    unsigned fv = 0xFFFFFFFFu;
    if (lane < 16) fv = ld_flagc(fp);
    while (!__all((int)(fv >= need))) {
      __builtin_amdgcn_s_sleep(1);
      if (lane < 16) fv = ld_flagc(fp);
    }

    // x strip (and dustbin entry, used by wave 0 only)
    float4 xv, xd4;
    ld2_coherent(xin + c0, xin + 4096, xv, xd4);

    // 16 row-partials over this lane's 4 cols
    float acc[16];
#pragma unroll
    for (int r = 0; r < 16; ++r) {
      const unsigned int aw = *reinterpret_cast<const unsigned int*>(Kl + r * 4096 + c0);
      const f32x2 lo = __builtin_amdgcn_cvt_pk_f32_fp8((int)aw, false);
      const f32x2 hi = __builtin_amdgcn_cvt_pk_f32_fp8((int)aw, true);
      acc[r] = lo.x * xv.x + lo.y * xv.y + hi.x * xv.z + hi.y * xv.w;
    }

    // fold-butterfly: 16 regs x 64 lanes -> lane rev4(lane&15) holds row sum
    float r8[8], r4[4], r2[2], r1;
    {
      const bool f0 = (lane & 1) != 0;
#pragma unroll
      for (int k = 0; k < 8; ++k) {
        const float send = f0 ? acc[k] : acc[k + 8];
        const float keep = f0 ? acc[k + 8] : acc[k];
        r8[k] = keep + __shfl_xor(send, 1, 64);
      }
      const bool f1 = (lane & 2) != 0;
#pragma unroll
      for (int k = 0; k < 4; ++k) {
        const float send = f1 ? r8[k] : r8[k + 4];
        const float keep = f1 ? r8[k + 4] : r8[k];
        r4[k] = keep + __shfl_xor(send, 2, 64);
      }
      const bool f2 = (lane & 4) != 0;
#pragma unroll
      for (int k = 0; k < 2; ++k) {
        const float send = f2 ? r4[k] : r4[k + 2];
        const float keep = f2 ? r4[k + 2] : r4[k];
        r2[k] = keep + __shfl_xor(send, 4, 64);
      }
      const bool f3 = (lane & 8) != 0;
      {
        const float send = f3 ? r2[0] : r2[1];
        const float keep = f3 ? r2[1] : r2[0];
        r1 = keep + __shfl_xor(send, 8, 64);
      }
      r1 += __shfl_xor(r1, 16, 64);
      r1 += __shfl_xor(r1, 32, 64);
    }
    if (lane < 16) scratch[sb][rev4][w] = r1;

    if (b == 0) {   // dustbin row needs sum of all x
      float sv = xv.x + xv.y + xv.z + xv.w;
      sv += __shfl_xor(sv, 1, 64);  sv += __shfl_xor(sv, 2, 64);
      sv += __shfl_xor(sv, 4, 64);  sv += __shfl_xor(sv, 8, 64);
      sv += __shfl_xor(sv, 16, 64); sv += __shfl_xor(sv, 32, 64);
      if (lane == 0) dscr[sb][w] = sv;
    }
    __syncthreads();

    if (w == 0) {   // finale: cross-wave sum, store outputs, publish flag
      const int rr = lane >> 2, wq = (lane & 3) * 4;
      float s = scratch[sb][rr][wq] + scratch[sb][rr][wq + 1]
              + scratch[sb][rr][wq + 2] + scratch[sb][rr][wq + 3];
      s += __shfl_xor(s, 1, 64);
      s += __shfl_xor(s, 2, 64);
      if ((lane & 3) == 0)
        st_coherent(xout + (b << 4) + rr, 1.0f / (s + E * xd4.x));
      if (b == 0) {
        float t = (lane < 16) ? dscr[sb][lane] : 0.f;
        t += __shfl_xor(t, 1, 64);  t += __shfl_xor(t, 2, 64);
        t += __shfl_xor(t, 4, 64);  t += __shfl_xor(t, 8, 64);
        t += __shfl_xor(t, 16, 64); t += __shfl_xor(t, 32, 64);
        if (lane == 0) st_coherent(xout + 4096, 1.0f / (E * (t + xd4.x)));
      }
      asm volatile("s_waitcnt vmcnt(0)" ::: "memory");   // outputs at coherence pt
      if (lane == 0) st_flag(flags + b, (unsigned)g);    // then publish
    }
  }
}

extern "C" void kernel_launch(void* const* d_in, const int* in_sizes, int n_in,
                              void* d_out, int out_size, void* d_ws, size_t ws_size,
                              hipStream_t stream) {
  const float* Q = (const float*)d_in[0];
  const float* R = (const float*)d_in[1];
  const float* z = (const float*)d_in[2];

  float* P = (float*)d_out;
  float* Kf = P + (size_t)MROWS * NCOLS;   // K-region of d_out

  unsigned char* A8 = (unsigned char*)d_ws;                   // 16.8 MB
  unsigned char* T8 = A8 + (size_t)MROWS * NCOLS;             // 16.8 MB
  float* xbuf = (float*)(T8 + (size_t)MROWS * NCOLS);         // 4 slots x 4104 f
  unsigned* flags = (unsigned*)(xbuf + 4 * XSLOT);            // 256 u32

  // gen 199 (last u) -> slot 3; gen 200 (last v) -> slot 0
  const float* u_final = xbuf + 3 * XSLOT;
  const float* v_final = xbuf;

  mfma_gemm_kernel<0><<<dim3(32, 32), 256, 0, stream>>>(Q, R, A8, T8, nullptr, nullptr, nullptr, nullptr);
  initv_kernel<<<5, 1024, 0, stream>>>(xbuf, flags);
  sinkhorn_persist_kernel<<<NBLK, 1024, 0, stream>>>(A8, T8, xbuf, z, flags);
  mfma_gemm_kernel<1><<<dim3(32, 32), 256, 0, stream>>>(Q, R, nullptr, nullptr, Kf, P, u_final, v_final);
  edgeK_kernel<<<(MP1 + 255) / 256, 256, 0, stream>>>(z, Kf, u_final, v_final);
}

// Round 7
// 1007.686 us; speedup vs baseline: 1.2296x; 1.2296x over previous
//
#include <hip/hip_runtime.h>
#include <hip/hip_bf16.h>

// Sinkhorn object matching, scaling-vector formulation, fp8 iteration,
// PERSISTENT kernel v3: per-gen write-once sync objects + L2-cached x ring.
//   S = Q R^T (4096x4096, D=256), K0 = exp(S_aug/0.1), dustbin row/col = z
//   100x: u = 1/(K0 v); v = 1/(K0^T u);  K = diag(u) K0 diag(v); P interior.
// Block b (256 blocks, 1024 thr) holds rows [16b,16b+16) of A8=fp8(K0) AND of
// T8=fp8(K0^T) in LDS. 1 block/CU -> 256 blocks co-resident.
// Gen g=1..200 writes x_g into ring slot g (write-once per dispatch) with
// sc0sc1 stores; consumers read it with sc0 (L2-cacheable: the slot's lines
// are first touched only after the done-flag, so no stale copies can exist).
// Arrival: atomic fetch_add on ctr[g][group] (8 lines, 64B apart); the
// ret==31 lane stores done8[g][group]. Release: wave 0 of each block polls
// the single 32B done8[g] line (8 dwords), then __syncthreads wakes the block.
// All sync objects are gen-indexed (monotonic, no resets) and zeroed by
// init_sync each call -> deterministic, replay-safe.

#define MROWS 4096
#define NCOLS 4096
#define DDIM 256
#define MP1 4097
#define INV_EPS 10.0f
#define NBLK 256
#define XSLOT 4160                 // floats per ring slot (16640 B, 64B mult)
#define CTR_DW 25728               // 201 gens * 128 dwords (8 groups * 16 dw)
#define DONE_DW 3216               // 201 gens * 16 dwords (8 used per gen)

typedef __attribute__((ext_vector_type(8))) short bf16x8;
typedef __attribute__((ext_vector_type(4))) float f32x4;
typedef __attribute__((ext_vector_type(2))) float f32x2;
typedef __attribute__((ext_vector_type(4))) unsigned short u16x4;

static __device__ __forceinline__ unsigned short f2bf(float f) {
  __hip_bfloat16 h = __float2bfloat16(f);
  union { __hip_bfloat16 h; unsigned short s; } c;
  c.h = h;
  return c.s;
}

// x-strip load: L1-bypass, L2-cacheable (slot lines are write-once -> no
// stale-L2 hazard). waitcnt inside the asm (rule #18).
static __device__ __forceinline__ void ld_strip_l2(const float* ps, const float* pd,
                                                   float4& xv, float& xd) {
  asm volatile("global_load_dwordx4 %0, %2, off sc0\n\t"
               "global_load_dword %1, %3, off sc0\n\t"
               "s_waitcnt vmcnt(0)"
               : "=v"(xv), "=v"(xd)
               : "v"(ps), "v"(pd)
               : "memory");
}
// coherent store to the device coherence point (LLC)
static __device__ __forceinline__ void st_coherent(float* p, float x) {
  asm volatile("global_store_dword %0, %1, off sc0 sc1" :: "v"(p), "v"(x) : "memory");
}
// uncached flag accessors
static __device__ __forceinline__ unsigned ld_flagc(const unsigned* p) {
  unsigned r;
  asm volatile("global_load_dword %0, %1, off sc0 sc1\n\t"
               "s_waitcnt vmcnt(0)"
               : "=v"(r) : "v"(p) : "memory");
  return r;
}
static __device__ __forceinline__ void st_flag(unsigned* p, unsigned x) {
  asm volatile("global_store_dword %0, %1, off sc0 sc1" :: "v"(p), "v"(x) : "memory");
}

// ---------------------------------------------------------------------------
// MFMA bf16 GEMM: 128x128 tile, 4 waves (2x2), wave = 64x64 via 4x4 frags of
// 16x16x32. MODE 0: kv=exp(10S) -> fp8 A8[row][col], fp8 T8[col][row].
// MODE 1: val = u[row]*exp(10S)*v[col] -> fp32 K (stride MP1) and P.
// ---------------------------------------------------------------------------
template <int MODE>
__global__ __launch_bounds__(256) void mfma_gemm_kernel(
    const float* __restrict__ Q, const float* __restrict__ R,
    unsigned char* __restrict__ A8, unsigned char* __restrict__ T8,
    float* __restrict__ Kf, float* __restrict__ P,
    const float* __restrict__ u, const float* __restrict__ v)
{
  __shared__ unsigned short Qs[128][40];
  __shared__ unsigned short Rs[128][40];

  const int tid = threadIdx.x;
  const int lane = tid & 63;
  const int wid = tid >> 6;
  const int wy = wid >> 1;
  const int wx = wid & 1;
  const int rb = blockIdx.y * 128;
  const int cb = blockIdx.x * 128;
  const int lr = tid >> 3;
  const int lf = (tid & 7) * 4;

  f32x4 acc[4][4];
#pragma unroll
  for (int m = 0; m < 4; ++m)
#pragma unroll
    for (int n = 0; n < 4; ++n)
      acc[m][n] = (f32x4){0.f, 0.f, 0.f, 0.f};

  for (int k0 = 0; k0 < DDIM; k0 += 32) {
    float4 qv[4], rv[4];
#pragma unroll
    for (int i = 0; i < 4; ++i) {
      qv[i] = *reinterpret_cast<const float4*>(&Q[(size_t)(rb + lr + 32 * i) * DDIM + k0 + lf]);
      rv[i] = *reinterpret_cast<const float4*>(&R[(size_t)(cb + lr + 32 * i) * DDIM + k0 + lf]);
    }
    __syncthreads();
#pragma unroll
    for (int i = 0; i < 4; ++i) {
      u16x4 qs = {f2bf(qv[i].x), f2bf(qv[i].y), f2bf(qv[i].z), f2bf(qv[i].w)};
      u16x4 rs = {f2bf(rv[i].x), f2bf(rv[i].y), f2bf(rv[i].z), f2bf(rv[i].w)};
      *reinterpret_cast<u16x4*>(&Qs[lr + 32 * i][lf]) = qs;
      *reinterpret_cast<u16x4*>(&Rs[lr + 32 * i][lf]) = rs;
    }
    __syncthreads();

    const int ko = (lane >> 4) * 8;
    const int fr = lane & 15;
    bf16x8 af[4], bg[4];
#pragma unroll
    for (int m = 0; m < 4; ++m)
      af[m] = *reinterpret_cast<const bf16x8*>(&Qs[wy * 64 + m * 16 + fr][ko]);
#pragma unroll
    for (int n = 0; n < 4; ++n)
      bg[n] = *reinterpret_cast<const bf16x8*>(&Rs[wx * 64 + n * 16 + fr][ko]);
#pragma unroll
    for (int m = 0; m < 4; ++m)
#pragma unroll
      for (int n = 0; n < 4; ++n)
        acc[m][n] = __builtin_amdgcn_mfma_f32_16x16x32_bf16(af[m], bg[n], acc[m][n], 0, 0, 0);
  }

  // C/D layout (16x16x32): col = lane&15, row = (lane>>4)*4 + reg.
  const int r0 = (lane >> 4) * 4;
  const int fc = lane & 15;
#pragma unroll
  for (int m = 0; m < 4; ++m) {
    const int row0 = rb + wy * 64 + m * 16 + r0;
    float uu[4];
    if (MODE == 1) {
#pragma unroll
      for (int r = 0; r < 4; ++r) uu[r] = u[row0 + r];
    }
#pragma unroll
    for (int n = 0; n < 4; ++n) {
      const int col = cb + wx * 64 + n * 16 + fc;
      if (MODE == 0) {
        float kv[4];
#pragma unroll
        for (int r = 0; r < 4; ++r) kv[r] = __expf(acc[m][n][r] * INV_EPS);
        int packed = __builtin_amdgcn_cvt_pk_fp8_f32(kv[0], kv[1], 0, false);
        packed = __builtin_amdgcn_cvt_pk_fp8_f32(kv[2], kv[3], packed, true);
        *reinterpret_cast<unsigned int*>(&T8[(size_t)col * NCOLS + row0]) = (unsigned int)packed;
#pragma unroll
        for (int r = 0; r < 4; ++r)
          A8[(size_t)(row0 + r) * NCOLS + col] = (unsigned char)(((unsigned int)packed >> (8 * r)) & 0xffu);
      } else {
        const float vc = v[col];
#pragma unroll
        for (int r = 0; r < 4; ++r) {
          const float kv = __expf(acc[m][n][r] * INV_EPS);
          const float val = uu[r] * kv * vc;
          Kf[(size_t)(row0 + r) * MP1 + col] = val;
          P[(size_t)(row0 + r) * NCOLS + col] = val;
        }
      }
    }
  }
}

// ---------------------------------------------------------------------------
// ring slot 0 = ones (gen 0 = initial v); zero all gen-indexed sync state.
// ---------------------------------------------------------------------------
__global__ void init_sync_kernel(float* __restrict__ xbuf, unsigned* __restrict__ ctr,
                                 unsigned* __restrict__ done8)
{
  const int i = blockIdx.x * 1024 + threadIdx.x;
  if (i < MP1) xbuf[i] = 1.0f;
  if (i < CTR_DW) ctr[i] = 0u;
  if (i < DONE_DW) done8[i] = 0u;
}

// ---------------------------------------------------------------------------
// Final K dustbin row/col.
// ---------------------------------------------------------------------------
__global__ void edgeK_kernel(const float* __restrict__ zp, float* __restrict__ Kf,
                             const float* __restrict__ u, const float* __restrict__ v)
{
  const int i = blockIdx.x * 256 + threadIdx.x;
  if (i >= MP1) return;
  const float E = __expf(zp[0] * INV_EPS);
  Kf[(size_t)i * MP1 + NCOLS] = u[i] * E * v[NCOLS];
  Kf[(size_t)MROWS * MP1 + i] = u[MROWS] * E * v[i];
}

// ---------------------------------------------------------------------------
// Persistent Sinkhorn iteration kernel. 256 blocks x 1024 threads.
// Per gen g: wave0 polls done8[g-1] (one 32B line), __syncthreads releases
// the block; waves load their x strip (sc0, L2-cached), compute 16 partials
// over their 256-col strip, fold-butterfly reduce, scratch; wave0 finale
// computes the block's 16 outputs, stores them to ring slot g (sc0sc1),
// vmcnt(0), then lane0 atomically arrives on ctr[g][group]; the ret==31
// arrival stores done8[g][group].
// ---------------------------------------------------------------------------
__global__ __launch_bounds__(1024) void sinkhorn_persist_kernel(
    const unsigned char* __restrict__ A8, const unsigned char* __restrict__ T8,
    float* __restrict__ xbuf, const float* __restrict__ zp,
    unsigned* __restrict__ ctr, unsigned* __restrict__ done8)
{
  __shared__ unsigned char lA[16 * 4096];
  __shared__ unsigned char lT[16 * 4096];
  __shared__ float scratch[2][16][17];
  __shared__ float dscr[2][16];

  const int tid = threadIdx.x;
  const int b = blockIdx.x;
  const int lane = tid & 63;
  const int w = tid >> 6;
  const float E = __expf(zp[0] * INV_EPS);
  const int rev4 = ((lane & 1) << 3) | ((lane & 2) << 1) | ((lane & 4) >> 1) | ((lane & 8) >> 3);

  // one-time: stage this block's A and T row-slices into LDS (64KB each)
  {
    const uint4* gA = reinterpret_cast<const uint4*>(A8 + (size_t)b * 16 * 4096);
    const uint4* gT = reinterpret_cast<const uint4*>(T8 + (size_t)b * 16 * 4096);
    uint4* sA = reinterpret_cast<uint4*>(lA);
    uint4* sT = reinterpret_cast<uint4*>(lT);
#pragma unroll
    for (int i = 0; i < 4; ++i) {
      sA[tid + 1024 * i] = gA[tid + 1024 * i];
      sT[tid + 1024 * i] = gT[tid + 1024 * i];
    }
  }
  __syncthreads();

  const int c0 = (w << 8) + (lane << 2);   // lane's 4-col strip base

  for (int g = 1; g <= 200; ++g) {
    const unsigned char* Kl = (g & 1) ? lA : lT;      // odd g: u = f(v) uses A
    const float* xin = xbuf + (size_t)(g - 1) * XSLOT;
    float* xout = xbuf + (size_t)g * XSLOT;
    const unsigned need = (unsigned)(g - 1);
    const int sb = g & 1;

    // ---- wait for gen g-1 (wave 0 polls the 8-dword done line) ----
    if (w == 0) {
      const unsigned* dp = done8 + (size_t)(g - 1) * 16 + (lane & 7);
      unsigned fv = ld_flagc(dp);
      while (!__all((int)(fv >= need))) {
        __builtin_amdgcn_s_sleep(1);
        fv = ld_flagc(dp);
      }
    }
    __syncthreads();

    // ---- load x strip (L2-cached) ----
    float4 xv; float xd;
    ld_strip_l2(xin + c0, xin + 4096, xv, xd);

    // ---- 16 row-partials over this lane's 4 cols ----
    float acc[16];
#pragma unroll
    for (int r = 0; r < 16; ++r) {
      const unsigned int aw = *reinterpret_cast<const unsigned int*>(Kl + r * 4096 + c0);
      const f32x2 lo = __builtin_amdgcn_cvt_pk_f32_fp8((int)aw, false);
      const f32x2 hi = __builtin_amdgcn_cvt_pk_f32_fp8((int)aw, true);
      acc[r] = lo.x * xv.x + lo.y * xv.y + hi.x * xv.z + hi.y * xv.w;
    }

    // ---- fold-butterfly: 16 regs x 64 lanes -> lane rev4(lane&15) ----
    float r8[8], r4[4], r2[2], r1;
    {
      const bool f0 = (lane & 1) != 0;
#pragma unroll
      for (int k = 0; k < 8; ++k) {
        const float send = f0 ? acc[k] : acc[k + 8];
        const float keep = f0 ? acc[k + 8] : acc[k];
        r8[k] = keep + __shfl_xor(send, 1, 64);
      }
      const bool f1 = (lane & 2) != 0;
#pragma unroll
      for (int k = 0; k < 4; ++k) {
        const float send = f1 ? r8[k] : r8[k + 4];
        const float keep = f1 ? r8[k + 4] : r8[k];
        r4[k] = keep + __shfl_xor(send, 2, 64);
      }
      const bool f2 = (lane & 4) != 0;
#pragma unroll
      for (int k = 0; k < 2; ++k) {
        const float send = f2 ? r4[k] : r4[k + 2];
        const float keep = f2 ? r4[k + 2] : r4[k];
        r2[k] = keep + __shfl_xor(send, 4, 64);
      }
      const bool f3 = (lane & 8) != 0;
      {
        const float send = f3 ? r2[0] : r2[1];
        const float keep = f3 ? r2[1] : r2[0];
        r1 = keep + __shfl_xor(send, 8, 64);
      }
      r1 += __shfl_xor(r1, 16, 64);
      r1 += __shfl_xor(r1, 32, 64);
    }
    if (lane < 16) scratch[sb][rev4][w] = r1;

    if (b == 0) {   // dustbin row needs sum of all x
      float sv = xv.x + xv.y + xv.z + xv.w;
      sv += __shfl_xor(sv, 1, 64);  sv += __shfl_xor(sv, 2, 64);
      sv += __shfl_xor(sv, 4, 64);  sv += __shfl_xor(sv, 8, 64);
      sv += __shfl_xor(sv, 16, 64); sv += __shfl_xor(sv, 32, 64);
      if (lane == 0) dscr[sb][w] = sv;
    }
    __syncthreads();

    // ---- finale: cross-wave sum, store outputs, publish arrival ----
    if (w == 0) {
      const int rr = lane >> 2, wq = (lane & 3) * 4;
      float s = scratch[sb][rr][wq] + scratch[sb][rr][wq + 1]
              + scratch[sb][rr][wq + 2] + scratch[sb][rr][wq + 3];
      s += __shfl_xor(s, 1, 64);
      s += __shfl_xor(s, 2, 64);
      if ((lane & 3) == 0)
        st_coherent(xout + (b << 4) + rr, 1.0f / (s + E * xd));
      if (b == 0) {
        float t = (lane < 16) ? dscr[sb][lane] : 0.f;
        t += __shfl_xor(t, 1, 64);  t += __shfl_xor(t, 2, 64);
        t += __shfl_xor(t, 4, 64);  t += __shfl_xor(t, 8, 64);
        t += __shfl_xor(t, 16, 64); t += __shfl_xor(t, 32, 64);
        if (lane == 0) st_coherent(xout + 4096, 1.0f / (E * (t + xd)));
      }
      asm volatile("s_waitcnt vmcnt(0)" ::: "memory");   // outputs at LLC
      if (lane == 0) {
        unsigned* cp = ctr + (size_t)g * 128 + ((unsigned)(b >> 5) << 4);
        const unsigned ret = __hip_atomic_fetch_add(cp, 1u, __ATOMIC_RELAXED,
                                                    __HIP_MEMORY_SCOPE_AGENT);
        if (ret == 31u)
          st_flag(done8 + (size_t)g * 16 + (b >> 5), (unsigned)g);
      }
    }
  }
}

extern "C" void kernel_launch(void* const* d_in, const int* in_sizes, int n_in,
                              void* d_out, int out_size, void* d_ws, size_t ws_size,
                              hipStream_t stream) {
  const float* Q = (const float*)d_in[0];
  const float* R = (const float*)d_in[1];
  const float* z = (const float*)d_in[2];

  float* P = (float*)d_out;
  float* Kf = P + (size_t)MROWS * NCOLS;   // K-region of d_out

  unsigned char* A8 = (unsigned char*)d_ws;                   // 16.8 MB
  unsigned char* T8 = A8 + (size_t)MROWS * NCOLS;             // 16.8 MB
  float* xbuf = (float*)(T8 + (size_t)MROWS * NCOLS);         // 201 slots
  unsigned* ctr = (unsigned*)(xbuf + (size_t)201 * XSLOT);    // 25728 u32
  unsigned* done8 = ctr + CTR_DW;                             // 3216 u32

  const float* u_final = xbuf + (size_t)199 * XSLOT;   // gen 199 = last u
  const float* v_final = xbuf + (size_t)200 * XSLOT;   // gen 200 = last v

  mfma_gemm_kernel<0><<<dim3(32, 32), 256, 0, stream>>>(Q, R, A8, T8, nullptr, nullptr, nullptr, nullptr);
  init_sync_kernel<<<26, 1024, 0, stream>>>(xbuf, ctr, done8);
  sinkhorn_persist_kernel<<<NBLK, 1024, 0, stream>>>(A8, T8, xbuf, z, ctr, done8);
  mfma_gemm_kernel<1><<<dim3(32, 32), 256, 0, stream>>>(Q, R, nullptr, nullptr, Kf, P, u_final, v_final);
  edgeK_kernel<<<(MP1 + 255) / 256, 256, 0, stream>>>(z, Kf, u_final, v_final);
}